// Round 13
// baseline (642.969 us; speedup 1.0000x reference)
//
#include <hip/hip_runtime.h>
#include <hip/hip_bf16.h>

typedef __attribute__((ext_vector_type(4))) int i32x4;
typedef __attribute__((ext_vector_type(16))) int i32x16;

#define M_DIM 8192
#define N_DIM 8192
#define K_DIM 2048
#define WCOUNT (N_DIM * K_DIM)

// Fragment-major layout: frag[t32][kc][l] : byte = t32*65536 + kc*512 + l*16.
// One 32x32x32 MFMA operand fragment = contiguous 1024-B wave access.

// ---------------- kernel 1: per-block partial sums of |w| ----------------
__global__ __launch_bounds__(256) void k_abs_partial(const float* __restrict__ w,
                                                     float* __restrict__ part) {
    int tid = blockIdx.x * 256 + threadIdx.x;
    const float4* w4 = (const float4*)w;
    float s = 0.0f;
    const int total4 = WCOUNT / 4;
    for (int i = tid; i < total4; i += 2048 * 256) {
        float4 v = w4[i];
        s += fabsf(v.x) + fabsf(v.y) + fabsf(v.z) + fabsf(v.w);
    }
    #pragma unroll
    for (int off = 1; off < 64; off <<= 1) s += __shfl_xor(s, off);
    __shared__ float red[4];
    if ((threadIdx.x & 63) == 0) red[threadIdx.x >> 6] = s;
    __syncthreads();
    if (threadIdx.x == 0)
        part[blockIdx.x] = (red[0] + red[1]) + (red[2] + red[3]);
}

// ---------------- kernel 2: deterministic final reduce -> sum|w| ----------------
__global__ __launch_bounds__(256) void k_abs_final(const float* __restrict__ part,
                                                   float* __restrict__ sum) {
    int t = threadIdx.x;
    float s = 0.0f;
    #pragma unroll
    for (int i = 0; i < 8; i++) s += part[t + i * 256];
    #pragma unroll
    for (int off = 1; off < 64; off <<= 1) s += __shfl_xor(s, off);
    __shared__ float red[4];
    if ((t & 63) == 0) red[t >> 6] = s;
    __syncthreads();
    if (t == 0) sum[0] = (red[0] + red[1]) + (red[2] + red[3]);
}

// -------- kernel 3: ternary weight quant -> int8, fragment-major --------
__global__ __launch_bounds__(256) void k_wquant(const float* __restrict__ w,
                                                const float* __restrict__ sum,
                                                signed char* __restrict__ wqf) {
    const float thr = 0.5f * (sum[0] * (1.0f / 16777216.0f));
    const int g = blockIdx.x * 256 + threadIdx.x;
    const int n = g >> 7;
    const int kc = g & 127;
    const float4* wr = (const float4*)(w + (size_t)n * K_DIM + kc * 16);
    union { signed char c[16]; uint4 v; } pk;
    #pragma unroll
    for (int q = 0; q < 4; q++) {
        float4 v = wr[q];
        pk.c[q * 4 + 0] = v.x > thr ? 1 : (v.x < -thr ? -1 : 0);
        pk.c[q * 4 + 1] = v.y > thr ? 1 : (v.y < -thr ? -1 : 0);
        pk.c[q * 4 + 2] = v.z > thr ? 1 : (v.z < -thr ? -1 : 0);
        pk.c[q * 4 + 3] = v.w > thr ? 1 : (v.w < -thr ? -1 : 0);
    }
    *(uint4*)(wqf + (size_t)(n >> 5) * 65536 + kc * 512 + (n & 31) * 16) = pk.v;
}

// -------- kernel 4: activation quant -> int8 fragment-major + scale --------
__global__ __launch_bounds__(256) void k_xquant(const float* __restrict__ x,
                                                signed char* __restrict__ xqf,
                                                float* __restrict__ scale) {
    const int row = blockIdx.x;
    const int t = threadIdx.x;
    const float4* xr = (const float4*)(x + (size_t)row * K_DIM);
    float4 a = xr[t * 2];
    float4 b = xr[t * 2 + 1];
    float m = fmaxf(fmaxf(fmaxf(fabsf(a.x), fabsf(a.y)), fmaxf(fabsf(a.z), fabsf(a.w))),
                    fmaxf(fmaxf(fabsf(b.x), fabsf(b.y)), fmaxf(fabsf(b.z), fabsf(b.w))));
    #pragma unroll
    for (int off = 1; off < 64; off <<= 1) m = fmaxf(m, __shfl_xor(m, off));
    __shared__ float red[4];
    if ((t & 63) == 0) red[t >> 6] = m;
    __syncthreads();
    m = fmaxf(fmaxf(red[0], red[1]), fmaxf(red[2], red[3]));
    const float sc = fmaxf(m, 1e-5f);
    if (t == 0) scale[row] = sc;
    const float r = 127.0f / sc;
    float q[8] = {a.x, a.y, a.z, a.w, b.x, b.y, b.z, b.w};
    union { signed char c[8]; uint2 v; } pk;
    #pragma unroll
    for (int j = 0; j < 8; j++) {
        float v = rintf(q[j] * r);
        v = fminf(fmaxf(v, -127.0f), 127.0f);
        pk.c[j] = (signed char)v;
    }
    *(uint2*)(xqf + (size_t)(row >> 5) * 65536 + (t >> 1) * 512
              + (row & 31) * 16 + (t & 1) * 8) = pk.v;
}

// ---------------- kernel 4b: per-row epilogue coefficient ----------------
__global__ __launch_bounds__(256) void k_coef(const float* __restrict__ sum,
                                              const float* __restrict__ scale,
                                              float* __restrict__ coef) {
    const int i = blockIdx.x * 256 + threadIdx.x;
    coef[i] = (sum[0] * (1.0f / 16777216.0f)) / scale[i];
}

#define GLDS16(g, l)                                                                   \
    __builtin_amdgcn_global_load_lds((const __attribute__((address_space(1))) void*)(g), \
                                     (__attribute__((address_space(3))) void*)(l), 16, 0, 0)
#define BAR __builtin_amdgcn_s_barrier()
#define VMW(n) asm volatile("s_waitcnt vmcnt(" #n ")" ::: "memory")

// ---------------- kernel 5: 128x128 i8 GEMM (BYTE-IDENTICAL to R12) ----------
__global__ __launch_bounds__(256, 3) void k_gemm(const signed char* __restrict__ xqf,
                                                 const signed char* __restrict__ wqf,
                                                 const float* __restrict__ coef,
                                                 float* __restrict__ out) {
    __shared__ signed char lds[49152];

    const int t = threadIdx.x;
    const int lane = t & 63;
    const int wid = t >> 6;
    const int wm = wid >> 1;
    const int wn = wid & 1;
    const int l31 = lane & 31;
    const int kg = lane >> 5;

    const int bid = blockIdx.x;
    const int xcd = bid & 7;
    const int idx = bid >> 3;
    const int grp = idx >> 5;
    const int w_ = idx & 31;
    const int bcol = grp * 4 + (w_ & 3);
    const int brow = xcd * 8 + ((w_ >> 2) & 7);

    const signed char* aSrc0 = xqf + (size_t)(brow * 4 + (t >> 7)) * 65536 + (t & 127) * 16;
    const signed char* aSrc1 = xqf + (size_t)(brow * 4 + 2 + (t >> 7)) * 65536 + (t & 127) * 16;
    const signed char* bSrc0 = wqf + (size_t)(bcol * 4 + (t >> 7)) * 65536 + (t & 127) * 16;
    const signed char* bSrc1 = wqf + (size_t)(bcol * 4 + 2 + (t >> 7)) * 65536 + (t & 127) * 16;
    const int dst0 = wid * 1024;
    const int dst1 = 4096 + wid * 1024;

#define STG(bufc, kt) do {                                                         \
        GLDS16(aSrc0 + (size_t)(kt) * 2048, lds + (bufc) * 16384 + dst0);          \
        GLDS16(aSrc1 + (size_t)(kt) * 2048, lds + (bufc) * 16384 + dst1);          \
        GLDS16(bSrc0 + (size_t)(kt) * 2048, lds + (bufc) * 16384 + 8192 + dst0);   \
        GLDS16(bSrc1 + (size_t)(kt) * 2048, lds + (bufc) * 16384 + 8192 + dst1);   \
    } while (0)

    const int aRd = wm * 4096 + lane * 16;
    const int bRd = 8192 + wn * 4096 + lane * 16;

    i32x16 acc00 = (i32x16){0,0,0,0,0,0,0,0,0,0,0,0,0,0,0,0};
    i32x16 acc01 = acc00, acc10 = acc00, acc11 = acc00;

#define MMK(bufc) do {                                                             \
        const int ab = (bufc) * 16384 + aRd;                                       \
        const int bb = (bufc) * 16384 + bRd;                                       \
        i32x4 a00 = *(const i32x4*)&lds[ab];                                       \
        i32x4 a10 = *(const i32x4*)&lds[ab + 2048];                                \
        i32x4 b00 = *(const i32x4*)&lds[bb];                                       \
        i32x4 b10 = *(const i32x4*)&lds[bb + 2048];                                \
        i32x4 a01 = *(const i32x4*)&lds[ab + 1024];                                \
        i32x4 a11 = *(const i32x4*)&lds[ab + 3072];                                \
        i32x4 b01 = *(const i32x4*)&lds[bb + 1024];                                \
        i32x4 b11 = *(const i32x4*)&lds[bb + 3072];                                \
        __builtin_amdgcn_s_setprio(1);                                             \
        acc00 = __builtin_amdgcn_mfma_i32_32x32x32_i8(a00, b00, acc00, 0, 0, 0);   \
        acc01 = __builtin_amdgcn_mfma_i32_32x32x32_i8(a00, b10, acc01, 0, 0, 0);   \
        acc10 = __builtin_amdgcn_mfma_i32_32x32x32_i8(a10, b00, acc10, 0, 0, 0);   \
        acc11 = __builtin_amdgcn_mfma_i32_32x32x32_i8(a10, b10, acc11, 0, 0, 0);   \
        acc00 = __builtin_amdgcn_mfma_i32_32x32x32_i8(a01, b01, acc00, 0, 0, 0);   \
        acc01 = __builtin_amdgcn_mfma_i32_32x32x32_i8(a01, b11, acc01, 0, 0, 0);   \
        acc10 = __builtin_amdgcn_mfma_i32_32x32x32_i8(a11, b01, acc10, 0, 0, 0);   \
        acc11 = __builtin_amdgcn_mfma_i32_32x32x32_i8(a11, b11, acc11, 0, 0, 0);   \
        __builtin_amdgcn_s_setprio(0); } while (0)

#define STEP(bufc, kt) do {                                                        \
        MMK(bufc);                                                                 \
        BAR;                                                                       \
        STG(bufc, (kt) + 3);                                                       \
        VMW(8);                                                                    \
        BAR; } while (0)

    STG(0, 0); STG(1, 1); STG(2, 2);
    VMW(8);
    BAR;

    #pragma unroll 1
    for (int j = 0; j < 9; j++) {
        const int kt = 3 * j;
        STEP(0, kt);
        STEP(1, kt + 1);
        STEP(2, kt + 2);
    }
    STEP(0, 27);
    STEP(1, 28);
    MMK(2); BAR; VMW(4); BAR;
    MMK(0); BAR; VMW(0); BAR;
    MMK(1);

    const int rb = brow * 128 + wm * 64 + 4 * kg;
    const int cb = bcol * 128 + wn * 64 + l31;
    #pragma unroll
    for (int mt = 0; mt < 2; mt++) {
        const i32x16 ac0 = mt ? acc10 : acc00;
        const i32x16 ac1 = mt ? acc11 : acc01;
        #pragma unroll
        for (int r = 0; r < 16; r++) {
            const int grow = rb + mt * 32 + (r & 3) + 8 * (r >> 2);
            const float c = coef[grow];
            float v0 = (float)ac0[r] * c; v0 = fmaxf(v0, 0.0f);
            float v1 = (float)ac1[r] * c; v1 = fmaxf(v1, 0.0f);
            __builtin_nontemporal_store(v0 * v0, &out[(size_t)grow * N_DIM + cb]);
            __builtin_nontemporal_store(v1 * v1, &out[(size_t)grow * N_DIM + cb + 32]);
        }
    }
}

// ---------------- DIAG A: full K-loop, NO epilogue stores ----------------
// Same body as k_gemm; epilogue replaced by liveness sink. bcol masked to stay
// in-bounds at larger grid. Per-cohort time vs k_gemm isolates epilogue cost.
__global__ __launch_bounds__(256, 3) void k_diag_full(const signed char* __restrict__ xqf,
                                                      const signed char* __restrict__ wqf,
                                                      float* __restrict__ sink) {
    __shared__ signed char lds[49152];
    const int t = threadIdx.x;
    const int lane = t & 63;
    const int wid = t >> 6;
    const int wm = wid >> 1;
    const int wn = wid & 1;

    const int bid = blockIdx.x;
    const int xcd = bid & 7;
    const int idx = bid >> 3;
    const int grp = (idx >> 5) & 15;          // masked: in-bounds for any grid
    const int w_ = idx & 31;
    const int bcol = grp * 4 + (w_ & 3);
    const int brow = xcd * 8 + ((w_ >> 2) & 7);

    const signed char* aSrc0 = xqf + (size_t)(brow * 4 + (t >> 7)) * 65536 + (t & 127) * 16;
    const signed char* aSrc1 = xqf + (size_t)(brow * 4 + 2 + (t >> 7)) * 65536 + (t & 127) * 16;
    const signed char* bSrc0 = wqf + (size_t)(bcol * 4 + (t >> 7)) * 65536 + (t & 127) * 16;
    const signed char* bSrc1 = wqf + (size_t)(bcol * 4 + 2 + (t >> 7)) * 65536 + (t & 127) * 16;
    const int dst0 = wid * 1024;
    const int dst1 = 4096 + wid * 1024;
    const int aRd = wm * 4096 + lane * 16;
    const int bRd = 8192 + wn * 4096 + lane * 16;

    i32x16 acc00 = (i32x16){0,0,0,0,0,0,0,0,0,0,0,0,0,0,0,0};
    i32x16 acc01 = acc00, acc10 = acc00, acc11 = acc00;

    STG(0, 0); STG(1, 1); STG(2, 2);
    VMW(8);
    BAR;
    #pragma unroll 1
    for (int j = 0; j < 9; j++) {
        const int kt = 3 * j;
        STEP(0, kt);
        STEP(1, kt + 1);
        STEP(2, kt + 2);
    }
    STEP(0, 27);
    STEP(1, 28);
    MMK(2); BAR; VMW(4); BAR;
    MMK(0); BAR; VMW(0); BAR;
    MMK(1);

    // liveness sink: keeps the whole MFMA chain live; never-taken store.
    if (acc00[0] + acc01[1] + acc10[2] + acc11[3] == 123456789) sink[0] = 1.0f;
}

// ---------------- DIAG B: MFMA + ds_read + barriers only (no staging/vmcnt) ----
__global__ __launch_bounds__(256, 3) void k_diag_mfma(float* __restrict__ sink) {
    __shared__ signed char lds[49152];
    const int t = threadIdx.x;
    const int lane = t & 63;
    const int wid = t >> 6;
    const int wm = wid >> 1;
    const int wn = wid & 1;
    const int aRd = wm * 4096 + lane * 16;
    const int bRd = 8192 + wn * 4096 + lane * 16;

    // zero LDS once (deterministic acc = 0)
    int4* lz = (int4*)lds;
    #pragma unroll
    for (int i = 0; i < 12; i++) lz[t + i * 256] = (int4){0, 0, 0, 0};
    __syncthreads();

    i32x16 acc00 = (i32x16){0,0,0,0,0,0,0,0,0,0,0,0,0,0,0,0};
    i32x16 acc01 = acc00, acc10 = acc00, acc11 = acc00;

    #pragma unroll 1
    for (int j = 0; j < 9; j++) {
        MMK(0); BAR; BAR;
        MMK(1); BAR; BAR;
        MMK(2); BAR; BAR;
    }
    MMK(0); BAR; BAR;
    MMK(1); BAR; BAR;
    MMK(2); BAR; BAR;
    MMK(0); BAR; BAR;
    MMK(1);

    if (acc00[0] + acc01[1] + acc10[2] + acc11[3] == 123456789) sink[0] = 1.0f;
#undef STG
#undef MMK
#undef STEP
}

// ---------------- launch ----------------
extern "C" void kernel_launch(void* const* d_in, const int* in_sizes, int n_in,
                              void* d_out, int out_size, void* d_ws, size_t ws_size,
                              hipStream_t stream) {
    const float* x = (const float*)d_in[0];   // [4,2048,2048] fp32
    const float* w = (const float*)d_in[1];   // [8192,2048] fp32
    float* out = (float*)d_out;               // [4,2048,8192] fp32

    char* ws = (char*)d_ws;
    float* sum   = (float*)ws;
    float* part  = (float*)(ws + 256);
    float* scale = (float*)(ws + 16384);
    float* coef  = (float*)(ws + 49152);
    signed char* xqf = (signed char*)(ws + 131072);
    signed char* wqf = (signed char*)(ws + 131072 + 16777216);

    k_abs_partial<<<2048, 256, 0, stream>>>(w, part);
    k_abs_final<<<1, 256, 0, stream>>>(part, sum);
    k_wquant<<<4096, 256, 0, stream>>>(w, sum, wqf);
    k_xquant<<<M_DIM, 256, 0, stream>>>(x, xqf, scale);
    k_coef<<<32, 256, 0, stream>>>(sum, scale, coef);
    k_gemm<<<dim3(4096), 256, 0, stream>>>(xqf, wqf, coef, out);
    // ---- diagnostics (timing read from rocprof top-5; outputs are sinks) ----
    k_diag_full<<<dim3(8192), 256, 0, stream>>>(xqf, wqf, part);
    k_diag_mfma<<<dim3(14336), 256, 0, stream>>>(part);
}

// Round 14
// 199.594 us; speedup vs baseline: 3.2214x; 3.2214x over previous
//
#include <hip/hip_runtime.h>
#include <hip/hip_bf16.h>

typedef __attribute__((ext_vector_type(4))) int i32x4;
typedef __attribute__((ext_vector_type(16))) int i32x16;
typedef __attribute__((ext_vector_type(4))) float f32x4;

#define M_DIM 8192
#define N_DIM 8192
#define K_DIM 2048
#define WCOUNT (N_DIM * K_DIM)

// Fragment-major layout: frag[t32][kc][l] : byte = t32*65536 + kc*512 + l*16.
// One 32x32x32 MFMA operand fragment = contiguous 1024-B wave access.

// ---------------- kernel 1: per-block partial sums of |w| ----------------
__global__ __launch_bounds__(256) void k_abs_partial(const float* __restrict__ w,
                                                     float* __restrict__ part) {
    int tid = blockIdx.x * 256 + threadIdx.x;
    const float4* w4 = (const float4*)w;
    float s = 0.0f;
    const int total4 = WCOUNT / 4;
    for (int i = tid; i < total4; i += 2048 * 256) {
        float4 v = w4[i];
        s += fabsf(v.x) + fabsf(v.y) + fabsf(v.z) + fabsf(v.w);
    }
    #pragma unroll
    for (int off = 1; off < 64; off <<= 1) s += __shfl_xor(s, off);
    __shared__ float red[4];
    if ((threadIdx.x & 63) == 0) red[threadIdx.x >> 6] = s;
    __syncthreads();
    if (threadIdx.x == 0)
        part[blockIdx.x] = (red[0] + red[1]) + (red[2] + red[3]);
}

// ---------------- kernel 2: deterministic final reduce -> sum|w| ----------------
__global__ __launch_bounds__(256) void k_abs_final(const float* __restrict__ part,
                                                   float* __restrict__ sum) {
    int t = threadIdx.x;
    float s = 0.0f;
    #pragma unroll
    for (int i = 0; i < 8; i++) s += part[t + i * 256];
    #pragma unroll
    for (int off = 1; off < 64; off <<= 1) s += __shfl_xor(s, off);
    __shared__ float red[4];
    if ((t & 63) == 0) red[t >> 6] = s;
    __syncthreads();
    if (t == 0) sum[0] = (red[0] + red[1]) + (red[2] + red[3]);
}

// -------- kernel 3: ternary weight quant -> int8, fragment-major --------
__global__ __launch_bounds__(256) void k_wquant(const float* __restrict__ w,
                                                const float* __restrict__ sum,
                                                signed char* __restrict__ wqf) {
    const float thr = 0.5f * (sum[0] * (1.0f / 16777216.0f));
    const int g = blockIdx.x * 256 + threadIdx.x;
    const int n = g >> 7;
    const int kc = g & 127;
    const float4* wr = (const float4*)(w + (size_t)n * K_DIM + kc * 16);
    union { signed char c[16]; uint4 v; } pk;
    #pragma unroll
    for (int q = 0; q < 4; q++) {
        float4 v = wr[q];
        pk.c[q * 4 + 0] = v.x > thr ? 1 : (v.x < -thr ? -1 : 0);
        pk.c[q * 4 + 1] = v.y > thr ? 1 : (v.y < -thr ? -1 : 0);
        pk.c[q * 4 + 2] = v.z > thr ? 1 : (v.z < -thr ? -1 : 0);
        pk.c[q * 4 + 3] = v.w > thr ? 1 : (v.w < -thr ? -1 : 0);
    }
    *(uint4*)(wqf + (size_t)(n >> 5) * 65536 + kc * 512 + (n & 31) * 16) = pk.v;
}

// -------- kernel 4: activation quant -> int8 fragment-major + scale + coef --------
__global__ __launch_bounds__(256) void k_xquant(const float* __restrict__ x,
                                                const float* __restrict__ sum,
                                                signed char* __restrict__ xqf,
                                                float* __restrict__ coef) {
    const int row = blockIdx.x;
    const int t = threadIdx.x;
    const float4* xr = (const float4*)(x + (size_t)row * K_DIM);
    float4 a = xr[t * 2];
    float4 b = xr[t * 2 + 1];
    float m = fmaxf(fmaxf(fmaxf(fabsf(a.x), fabsf(a.y)), fmaxf(fabsf(a.z), fabsf(a.w))),
                    fmaxf(fmaxf(fabsf(b.x), fabsf(b.y)), fmaxf(fabsf(b.z), fabsf(b.w))));
    #pragma unroll
    for (int off = 1; off < 64; off <<= 1) m = fmaxf(m, __shfl_xor(m, off));
    __shared__ float red[4];
    if ((t & 63) == 0) red[t >> 6] = m;
    __syncthreads();
    m = fmaxf(fmaxf(red[0], red[1]), fmaxf(red[2], red[3]));
    const float sc = fmaxf(m, 1e-5f);
    if (t == 0) coef[row] = (sum[0] * (1.0f / 16777216.0f)) / sc;
    const float r = 127.0f / sc;
    float q[8] = {a.x, a.y, a.z, a.w, b.x, b.y, b.z, b.w};
    union { signed char c[8]; uint2 v; } pk;
    #pragma unroll
    for (int j = 0; j < 8; j++) {
        float v = rintf(q[j] * r);
        v = fminf(fmaxf(v, -127.0f), 127.0f);
        pk.c[j] = (signed char)v;
    }
    *(uint2*)(xqf + (size_t)(row >> 5) * 65536 + (t >> 1) * 512
              + (row & 31) * 16 + (t & 1) * 8) = pk.v;
}

#define GLDS16(g, l)                                                                   \
    __builtin_amdgcn_global_load_lds((const __attribute__((address_space(1))) void*)(g), \
                                     (__attribute__((address_space(3))) void*)(l), 16, 0, 0)
#define BAR __builtin_amdgcn_s_barrier()
#define VMW(n) asm volatile("s_waitcnt vmcnt(" #n ")" ::: "memory")

// ---------------- kernel 5: 128x128 i8 GEMM (R12 K-loop + transposed epilogue) ----
// K-loop byte-identical to R12 (best measured: 3 blocks/CU, 3-buf ring, counted
// vmcnt(8), 50.6% MfmaUtil without epilogue per R13 diag). Epilogue rebuilt per
// R13 measurement (4.5 us/round, store-instruction-bound): acc is scattered as
// fp32 into a [64][128] LDS image per wm-half (consecutive lanes -> consecutive
// dwords, conflict-free), then all threads re-read row-contiguous float4 and
// store 512-B coalesced nontemporal dwordx4 runs (16 store-instr/thread vs 64).
__global__ __launch_bounds__(256, 3) void k_gemm(const signed char* __restrict__ xqf,
                                                 const signed char* __restrict__ wqf,
                                                 const float* __restrict__ coef,
                                                 float* __restrict__ out) {
    __shared__ signed char lds[49152];

    const int t = threadIdx.x;
    const int lane = t & 63;
    const int wid = t >> 6;
    const int wm = wid >> 1;
    const int wn = wid & 1;
    const int l31 = lane & 31;
    const int kg = lane >> 5;

    const int bid = blockIdx.x;
    const int xcd = bid & 7;
    const int idx = bid >> 3;
    const int grp = idx >> 5;
    const int w_ = idx & 31;
    const int bcol = grp * 4 + (w_ & 3);
    const int brow = xcd * 8 + ((w_ >> 2) & 7);

    const signed char* aSrc0 = xqf + (size_t)(brow * 4 + (t >> 7)) * 65536 + (t & 127) * 16;
    const signed char* aSrc1 = xqf + (size_t)(brow * 4 + 2 + (t >> 7)) * 65536 + (t & 127) * 16;
    const signed char* bSrc0 = wqf + (size_t)(bcol * 4 + (t >> 7)) * 65536 + (t & 127) * 16;
    const signed char* bSrc1 = wqf + (size_t)(bcol * 4 + 2 + (t >> 7)) * 65536 + (t & 127) * 16;
    const int dst0 = wid * 1024;
    const int dst1 = 4096 + wid * 1024;

#define STG(bufc, kt) do {                                                         \
        GLDS16(aSrc0 + (size_t)(kt) * 2048, lds + (bufc) * 16384 + dst0);          \
        GLDS16(aSrc1 + (size_t)(kt) * 2048, lds + (bufc) * 16384 + dst1);          \
        GLDS16(bSrc0 + (size_t)(kt) * 2048, lds + (bufc) * 16384 + 8192 + dst0);   \
        GLDS16(bSrc1 + (size_t)(kt) * 2048, lds + (bufc) * 16384 + 8192 + dst1);   \
    } while (0)

    const int aRd = wm * 4096 + lane * 16;
    const int bRd = 8192 + wn * 4096 + lane * 16;

    i32x16 acc00 = (i32x16){0,0,0,0,0,0,0,0,0,0,0,0,0,0,0,0};
    i32x16 acc01 = acc00, acc10 = acc00, acc11 = acc00;

#define MMK(bufc) do {                                                             \
        const int ab = (bufc) * 16384 + aRd;                                       \
        const int bb = (bufc) * 16384 + bRd;                                       \
        i32x4 a00 = *(const i32x4*)&lds[ab];                                       \
        i32x4 a10 = *(const i32x4*)&lds[ab + 2048];                                \
        i32x4 b00 = *(const i32x4*)&lds[bb];                                       \
        i32x4 b10 = *(const i32x4*)&lds[bb + 2048];                                \
        i32x4 a01 = *(const i32x4*)&lds[ab + 1024];                                \
        i32x4 a11 = *(const i32x4*)&lds[ab + 3072];                                \
        i32x4 b01 = *(const i32x4*)&lds[bb + 1024];                                \
        i32x4 b11 = *(const i32x4*)&lds[bb + 3072];                                \
        __builtin_amdgcn_s_setprio(1);                                             \
        acc00 = __builtin_amdgcn_mfma_i32_32x32x32_i8(a00, b00, acc00, 0, 0, 0);   \
        acc01 = __builtin_amdgcn_mfma_i32_32x32x32_i8(a00, b10, acc01, 0, 0, 0);   \
        acc10 = __builtin_amdgcn_mfma_i32_32x32x32_i8(a10, b00, acc10, 0, 0, 0);   \
        acc11 = __builtin_amdgcn_mfma_i32_32x32x32_i8(a10, b10, acc11, 0, 0, 0);   \
        acc00 = __builtin_amdgcn_mfma_i32_32x32x32_i8(a01, b01, acc00, 0, 0, 0);   \
        acc01 = __builtin_amdgcn_mfma_i32_32x32x32_i8(a01, b11, acc01, 0, 0, 0);   \
        acc10 = __builtin_amdgcn_mfma_i32_32x32x32_i8(a11, b01, acc10, 0, 0, 0);   \
        acc11 = __builtin_amdgcn_mfma_i32_32x32x32_i8(a11, b11, acc11, 0, 0, 0);   \
        __builtin_amdgcn_s_setprio(0); } while (0)

#define STEP(bufc, kt) do {                                                        \
        MMK(bufc);                                                                 \
        BAR;                                                                       \
        STG(bufc, (kt) + 3);                                                       \
        VMW(8);                                                                    \
        BAR; } while (0)

    STG(0, 0); STG(1, 1); STG(2, 2);
    VMW(8);
    BAR;

    #pragma unroll 1
    for (int j = 0; j < 9; j++) {
        const int kt = 3 * j;
        STEP(0, kt);
        STEP(1, kt + 1);
        STEP(2, kt + 2);
    }
    STEP(0, 27);
    STEP(1, 28);
    MMK(2); BAR; VMW(4); BAR;
    MMK(0); BAR; VMW(0); BAR;
    MMK(1);
    BAR;   // all waves done reading buf1 before epilogue reuses LDS

    // ---- transposed epilogue ----
    // Per wm-half h: waves with wm==h scatter fp32(acc) into lf[64][128]
    // (consecutive lanes -> consecutive dwords, conflict-free); barrier; all 256
    // threads read row-contiguous float4, apply coef/relu^2, store 512-B runs.
    float* lf = (float*)lds;
    f32x4* lf4 = (f32x4*)lds;
    #pragma unroll
    for (int h = 0; h < 2; h++) {
        if (wm == h) {
            #pragma unroll
            for (int mt = 0; mt < 2; mt++) {
                const i32x16 ac0 = mt ? acc10 : acc00;
                const i32x16 ac1 = mt ? acc11 : acc01;
                #pragma unroll
                for (int r = 0; r < 16; r++) {
                    const int lrow = mt * 32 + (r & 3) + 8 * (r >> 2) + 4 * kg;
                    lf[lrow * 128 + wn * 64 + l31]      = (float)ac0[r];
                    lf[lrow * 128 + wn * 64 + 32 + l31] = (float)ac1[r];
                }
            }
        }
        BAR;
        #pragma unroll
        for (int it = 0; it < 8; it++) {
            const int idx2 = it * 256 + t;
            const int row = idx2 >> 5;            // 0..63
            const int q = idx2 & 31;              // 16-B quad within row
            const int grow = brow * 128 + h * 64 + row;
            const float c = coef[grow];
            f32x4 v = lf4[row * 32 + q];
            #pragma unroll
            for (int e = 0; e < 4; e++) {
                float z = fmaxf(v[e] * c, 0.0f);
                v[e] = z * z;
            }
            __builtin_nontemporal_store(v, (f32x4*)&out[(size_t)grow * N_DIM
                                                        + bcol * 128 + q * 4]);
        }
        BAR;
    }
#undef STG
#undef MMK
#undef STEP
}

// ---------------- launch ----------------
extern "C" void kernel_launch(void* const* d_in, const int* in_sizes, int n_in,
                              void* d_out, int out_size, void* d_ws, size_t ws_size,
                              hipStream_t stream) {
    const float* x = (const float*)d_in[0];   // [4,2048,2048] fp32
    const float* w = (const float*)d_in[1];   // [8192,2048] fp32
    float* out = (float*)d_out;               // [4,2048,8192] fp32

    char* ws = (char*)d_ws;
    float* sum   = (float*)ws;
    float* part  = (float*)(ws + 256);
    float* coef  = (float*)(ws + 49152);
    signed char* xqf = (signed char*)(ws + 131072);
    signed char* wqf = (signed char*)(ws + 131072 + 16777216);

    k_abs_partial<<<2048, 256, 0, stream>>>(w, part);
    k_abs_final<<<1, 256, 0, stream>>>(part, sum);
    k_wquant<<<4096, 256, 0, stream>>>(w, sum, wqf);
    k_xquant<<<M_DIM, 256, 0, stream>>>(x, sum, xqf, coef);
    k_gemm<<<dim3(4096), 256, 0, stream>>>(xqf, wqf, coef, out);
}

// Round 15
// 194.362 us; speedup vs baseline: 3.3081x; 1.0269x over previous
//
#include <hip/hip_runtime.h>
#include <hip/hip_bf16.h>

typedef __attribute__((ext_vector_type(4))) int i32x4;
typedef __attribute__((ext_vector_type(16))) int i32x16;

#define M_DIM 8192
#define N_DIM 8192
#define K_DIM 2048
#define WCOUNT (N_DIM * K_DIM)

// Fragment-major layout: frag[t32][kc][l] : byte = t32*65536 + kc*512 + l*16.
// One 32x32x32 MFMA operand fragment = contiguous 1024-B wave access.

// ---------------- kernel 1: per-block partial sums of |w| ----------------
__global__ __launch_bounds__(256) void k_abs_partial(const float* __restrict__ w,
                                                     float* __restrict__ part) {
    int tid = blockIdx.x * 256 + threadIdx.x;
    const float4* w4 = (const float4*)w;
    float s = 0.0f;
    const int total4 = WCOUNT / 4;
    for (int i = tid; i < total4; i += 2048 * 256) {
        float4 v = w4[i];
        s += fabsf(v.x) + fabsf(v.y) + fabsf(v.z) + fabsf(v.w);
    }
    #pragma unroll
    for (int off = 1; off < 64; off <<= 1) s += __shfl_xor(s, off);
    __shared__ float red[4];
    if ((threadIdx.x & 63) == 0) red[threadIdx.x >> 6] = s;
    __syncthreads();
    if (threadIdx.x == 0)
        part[blockIdx.x] = (red[0] + red[1]) + (red[2] + red[3]);
}

// ---------------- kernel 2: deterministic final reduce -> sum|w| ----------------
__global__ __launch_bounds__(256) void k_abs_final(const float* __restrict__ part,
                                                   float* __restrict__ sum) {
    int t = threadIdx.x;
    float s = 0.0f;
    #pragma unroll
    for (int i = 0; i < 8; i++) s += part[t + i * 256];
    #pragma unroll
    for (int off = 1; off < 64; off <<= 1) s += __shfl_xor(s, off);
    __shared__ float red[4];
    if ((t & 63) == 0) red[t >> 6] = s;
    __syncthreads();
    if (t == 0) sum[0] = (red[0] + red[1]) + (red[2] + red[3]);
}

// -------- kernel 3: ternary weight quant -> int8, fragment-major --------
__global__ __launch_bounds__(256) void k_wquant(const float* __restrict__ w,
                                                const float* __restrict__ sum,
                                                signed char* __restrict__ wqf) {
    const float thr = 0.5f * (sum[0] * (1.0f / 16777216.0f));
    const int g = blockIdx.x * 256 + threadIdx.x;
    const int n = g >> 7;
    const int kc = g & 127;
    const float4* wr = (const float4*)(w + (size_t)n * K_DIM + kc * 16);
    union { signed char c[16]; uint4 v; } pk;
    #pragma unroll
    for (int q = 0; q < 4; q++) {
        float4 v = wr[q];
        pk.c[q * 4 + 0] = v.x > thr ? 1 : (v.x < -thr ? -1 : 0);
        pk.c[q * 4 + 1] = v.y > thr ? 1 : (v.y < -thr ? -1 : 0);
        pk.c[q * 4 + 2] = v.z > thr ? 1 : (v.z < -thr ? -1 : 0);
        pk.c[q * 4 + 3] = v.w > thr ? 1 : (v.w < -thr ? -1 : 0);
    }
    *(uint4*)(wqf + (size_t)(n >> 5) * 65536 + kc * 512 + (n & 31) * 16) = pk.v;
}

// -------- kernel 4: activation quant -> int8 fragment-major + coef --------
__global__ __launch_bounds__(256) void k_xquant(const float* __restrict__ x,
                                                const float* __restrict__ sum,
                                                signed char* __restrict__ xqf,
                                                float* __restrict__ coef) {
    const int row = blockIdx.x;
    const int t = threadIdx.x;
    const float4* xr = (const float4*)(x + (size_t)row * K_DIM);
    float4 a = xr[t * 2];
    float4 b = xr[t * 2 + 1];
    float m = fmaxf(fmaxf(fmaxf(fabsf(a.x), fabsf(a.y)), fmaxf(fabsf(a.z), fabsf(a.w))),
                    fmaxf(fmaxf(fabsf(b.x), fabsf(b.y)), fmaxf(fabsf(b.z), fabsf(b.w))));
    #pragma unroll
    for (int off = 1; off < 64; off <<= 1) m = fmaxf(m, __shfl_xor(m, off));
    __shared__ float red[4];
    if ((t & 63) == 0) red[t >> 6] = m;
    __syncthreads();
    m = fmaxf(fmaxf(red[0], red[1]), fmaxf(red[2], red[3]));
    const float sc = fmaxf(m, 1e-5f);
    if (t == 0) coef[row] = (sum[0] * (1.0f / 16777216.0f)) / sc;
    const float r = 127.0f / sc;
    float q[8] = {a.x, a.y, a.z, a.w, b.x, b.y, b.z, b.w};
    union { signed char c[8]; uint2 v; } pk;
    #pragma unroll
    for (int j = 0; j < 8; j++) {
        float v = rintf(q[j] * r);
        v = fminf(fmaxf(v, -127.0f), 127.0f);
        pk.c[j] = (signed char)v;
    }
    *(uint2*)(xqf + (size_t)(row >> 5) * 65536 + (t >> 1) * 512
              + (row & 31) * 16 + (t & 1) * 8) = pk.v;
}

#define GLDS16(g, l)                                                                   \
    __builtin_amdgcn_global_load_lds((const __attribute__((address_space(1))) void*)(g), \
                                     (__attribute__((address_space(3))) void*)(l), 16, 0, 0)
#define BAR __builtin_amdgcn_s_barrier()
#define VMW(n) asm volatile("s_waitcnt vmcnt(" #n ")" ::: "memory")

// ---------------- kernel 5: 128x128 i8 GEMM, 4 blocks/CU, 2-buf ring ----------
// R12 K-loop discipline (best measured: MMK; BAR; STG; counted-vmcnt; BAR) and
// R12 direct-store epilogue (R14's LDS-transposed epilogue REGRESSED: it moved
// store cost onto the contended LDS port). Delta vs R12: 2-buffer ring (32 KB
// LDS) -> 4 blocks/CU: more cross-block epilogue/K-loop overlap (the only lever
// that measurably moved R8->R9, R11->R12), 4 barrier domains, and grid = exactly
// 4 resident rounds (R12 had a 0.33-round straggler tail).
// Ledger: gate vmcnt(4) after STG(buf,kt+2) leaves kt+2's 4 outstanding, forcing
// kt+1 (staged 1 step ~800cy earlier >> L2 latency). WAR: restage issues after
// the read-barrier (reads lgkm-forced before each wave's MFMAs -> before BAR).
__global__ __launch_bounds__(256, 4) void k_gemm(const signed char* __restrict__ xqf,
                                                 const signed char* __restrict__ wqf,
                                                 const float* __restrict__ coef,
                                                 float* __restrict__ out) {
    __shared__ signed char lds[32768];

    const int t = threadIdx.x;
    const int lane = t & 63;
    const int wid = t >> 6;
    const int wm = wid >> 1;
    const int wn = wid & 1;
    const int l31 = lane & 31;
    const int kg = lane >> 5;

    // L2 mapping: XCD x owns brows [8x,8x+8); per XCD, groups of 4 bcols sweep.
    const int bid = blockIdx.x;
    const int xcd = bid & 7;
    const int idx = bid >> 3;
    const int grp = idx >> 5;
    const int w_ = idx & 31;
    const int bcol = grp * 4 + (w_ & 3);
    const int brow = xcd * 8 + ((w_ >> 2) & 7);

    const signed char* aSrc0 = xqf + (size_t)(brow * 4 + (t >> 7)) * 65536 + (t & 127) * 16;
    const signed char* aSrc1 = xqf + (size_t)(brow * 4 + 2 + (t >> 7)) * 65536 + (t & 127) * 16;
    const signed char* bSrc0 = wqf + (size_t)(bcol * 4 + (t >> 7)) * 65536 + (t & 127) * 16;
    const signed char* bSrc1 = wqf + (size_t)(bcol * 4 + 2 + (t >> 7)) * 65536 + (t & 127) * 16;
    const int dst0 = wid * 1024;
    const int dst1 = 4096 + wid * 1024;

#define STG(bufc, kt) do {                                                         \
        GLDS16(aSrc0 + (size_t)(kt) * 2048, lds + (bufc) * 16384 + dst0);          \
        GLDS16(aSrc1 + (size_t)(kt) * 2048, lds + (bufc) * 16384 + dst1);          \
        GLDS16(bSrc0 + (size_t)(kt) * 2048, lds + (bufc) * 16384 + 8192 + dst0);   \
        GLDS16(bSrc1 + (size_t)(kt) * 2048, lds + (bufc) * 16384 + 8192 + dst1);   \
    } while (0)

    const int aRd = wm * 4096 + lane * 16;
    const int bRd = 8192 + wn * 4096 + lane * 16;

    i32x16 acc00 = (i32x16){0,0,0,0,0,0,0,0,0,0,0,0,0,0,0,0};
    i32x16 acc01 = acc00, acc10 = acc00, acc11 = acc00;

#define MMK(bufc) do {                                                             \
        const int ab = (bufc) * 16384 + aRd;                                       \
        const int bb = (bufc) * 16384 + bRd;                                       \
        i32x4 a00 = *(const i32x4*)&lds[ab];                                       \
        i32x4 a10 = *(const i32x4*)&lds[ab + 2048];                                \
        i32x4 b00 = *(const i32x4*)&lds[bb];                                       \
        i32x4 b10 = *(const i32x4*)&lds[bb + 2048];                                \
        i32x4 a01 = *(const i32x4*)&lds[ab + 1024];                                \
        i32x4 a11 = *(const i32x4*)&lds[ab + 3072];                                \
        i32x4 b01 = *(const i32x4*)&lds[bb + 1024];                                \
        i32x4 b11 = *(const i32x4*)&lds[bb + 3072];                                \
        __builtin_amdgcn_s_setprio(1);                                             \
        acc00 = __builtin_amdgcn_mfma_i32_32x32x32_i8(a00, b00, acc00, 0, 0, 0);   \
        acc01 = __builtin_amdgcn_mfma_i32_32x32x32_i8(a00, b10, acc01, 0, 0, 0);   \
        acc10 = __builtin_amdgcn_mfma_i32_32x32x32_i8(a10, b00, acc10, 0, 0, 0);   \
        acc11 = __builtin_amdgcn_mfma_i32_32x32x32_i8(a10, b10, acc11, 0, 0, 0);   \
        acc00 = __builtin_amdgcn_mfma_i32_32x32x32_i8(a01, b01, acc00, 0, 0, 0);   \
        acc01 = __builtin_amdgcn_mfma_i32_32x32x32_i8(a01, b11, acc01, 0, 0, 0);   \
        acc10 = __builtin_amdgcn_mfma_i32_32x32x32_i8(a11, b01, acc10, 0, 0, 0);   \
        acc11 = __builtin_amdgcn_mfma_i32_32x32x32_i8(a11, b11, acc11, 0, 0, 0);   \
        __builtin_amdgcn_s_setprio(0); } while (0)

    // ---- prologue: kt0 -> buf0, kt1 -> buf1; force kt0 (leave kt1's 4 in flight).
    STG(0, 0);
    STG(1, 1);
    VMW(4);
    BAR;

    #pragma unroll 1
    for (int j = 0; j < 15; j++) {
        const int kt = 2 * j;
        MMK(0); BAR;
        STG(0, kt + 2); VMW(4);   // forces kt+1 (1-step flight)
        BAR;
        MMK(1); BAR;
        STG(1, kt + 3); VMW(4);   // forces kt+2
        BAR;
    }
    // tail: kt30 (buf0), kt31 (buf1)
    MMK(0); BAR;
    VMW(0);                       // forces kt31
    BAR;
    MMK(1);

    // ---- epilogue: out = (max(acc * coef[row], 0))^2, direct nontemporal stores.
    // 32x32 C/D: col = lane&31, row = (r&3) + 8*(r>>2) + 4*(lane>>5)
    const int rb = brow * 128 + wm * 64 + 4 * kg;
    const int cb = bcol * 128 + wn * 64 + l31;
    #pragma unroll
    for (int mt = 0; mt < 2; mt++) {
        const i32x16 ac0 = mt ? acc10 : acc00;
        const i32x16 ac1 = mt ? acc11 : acc01;
        #pragma unroll
        for (int r = 0; r < 16; r++) {
            const int grow = rb + mt * 32 + (r & 3) + 8 * (r >> 2);
            const float c = coef[grow];
            float v0 = (float)ac0[r] * c; v0 = fmaxf(v0, 0.0f);
            float v1 = (float)ac1[r] * c; v1 = fmaxf(v1, 0.0f);
            __builtin_nontemporal_store(v0 * v0, &out[(size_t)grow * N_DIM + cb]);
            __builtin_nontemporal_store(v1 * v1, &out[(size_t)grow * N_DIM + cb + 32]);
        }
    }
#undef STG
#undef MMK
}

// ---------------- launch ----------------
extern "C" void kernel_launch(void* const* d_in, const int* in_sizes, int n_in,
                              void* d_out, int out_size, void* d_ws, size_t ws_size,
                              hipStream_t stream) {
    const float* x = (const float*)d_in[0];   // [4,2048,2048] fp32
    const float* w = (const float*)d_in[1];   // [8192,2048] fp32
    float* out = (float*)d_out;               // [4,2048,8192] fp32

    char* ws = (char*)d_ws;
    float* sum   = (float*)ws;
    float* part  = (float*)(ws + 256);
    float* coef  = (float*)(ws + 49152);
    signed char* xqf = (signed char*)(ws + 131072);
    signed char* wqf = (signed char*)(ws + 131072 + 16777216);

    k_abs_partial<<<2048, 256, 0, stream>>>(w, part);
    k_abs_final<<<1, 256, 0, stream>>>(part, sum);
    k_wquant<<<4096, 256, 0, stream>>>(w, sum, wqf);
    k_xquant<<<M_DIM, 256, 0, stream>>>(x, sum, xqf, coef);
    k_gemm<<<dim3(4096), 256, 0, stream>>>(xqf, wqf, coef, out);
}